// Round 8
// baseline (135.241 us; speedup 1.0000x reference)
//
#include <hip/hip_runtime.h>
#include <hip/hip_cooperative_groups.h>
#include <math.h>
#include <stdint.h>

namespace cg = cooperative_groups;

// Problem constants (from reference): B=32, A=3, S=52, C=80
constexpr int NCELL = 32 * 3 * 52 * 52;   // 259584
constexpr int PS = 85;                    // prediction channels (5 + C)

constexpr int CPW  = 16;                  // cells per wave-chunk
constexpr int NWC  = NCELL / CPW;         // 16224 wave-chunks
constexpr int GRID = 512;                 // 2 blocks/CU * 256 CU (all co-resident)
constexpr int TPB  = 256;                 // 4 waves
constexpr int NWAVES = GRID * 4;          // 2048
constexpr int PRED_DW_W = CPW * PS;       // 1360 dwords per wave-chunk (5440 B)
constexpr int TGT_DW_W  = CPW * 6;        // 96 dwords per wave-chunk

// d_ws: per-block partials, 8 floats (32 B) per block; GRID slots (16 KB).
// [b*8 + 0..5] = {bce_noobj, n_noobj, obj_term, n_obj, box_se, nll}

typedef __attribute__((address_space(3))) uint32_t       lds_u32_t;
typedef __attribute__((address_space(1))) const uint32_t glb_u32_t;

__global__ __launch_bounds__(TPB, 2) void yolo_fused(const float* __restrict__ pred,
                                                     const float* __restrict__ tgt,
                                                     float* __restrict__ part,
                                                     float* __restrict__ out)
{
    // per-wave private triple-buffered staging (no cross-wave sharing -> no
    // in-loop barriers; per-wave counted vmcnt is exact)
    __shared__ float sp[4][3][PRED_DW_W];   // 65280 B
    __shared__ float st[4][3][TGT_DW_W];    //  4608 B
    __shared__ float red[4][6];

    const int tid  = threadIdx.x;
    const int wid  = tid >> 6;
    const int lane = tid & 63;
    const int c    = lane >> 2;   // cell within wave-chunk (0..15)
    const int g    = lane & 3;    // lane within 4-lane cell group

    const int gw = blockIdx.x * 4 + wid;                 // global wave id
    const int n  = (NWC - gw + (NWAVES - 1)) / NWAVES;   // chunks for this wave (7 or 8)

    float s0=0.f, s1=0.f, s2=0.f, s3=0.f, s4=0.f, s5=0.f;

    // ---- stage one wave-chunk into per-wave buffer b: exactly 7 VMEM instrs ----
    auto STAGE = [&](int b, int ck) {
        const uint32_t* gp = (const uint32_t*)pred + (size_t)ck * PRED_DW_W;
        #pragma unroll
        for (int it = 0; it < 5; ++it) {
            int d = (it * 64 + lane) * 4;
            __builtin_amdgcn_global_load_lds((glb_u32_t*)(gp + d),
                                             (lds_u32_t*)(&sp[wid][b][d]), 16, 0, 0);
        }
        if (lane < 20) {   // tail: 340 v4 = 5*64 + 20
            int d = (320 + lane) * 4;
            __builtin_amdgcn_global_load_lds((glb_u32_t*)(gp + d),
                                             (lds_u32_t*)(&sp[wid][b][d]), 16, 0, 0);
        }
        const uint32_t* gt = (const uint32_t*)tgt + (size_t)ck * TGT_DW_W;
        if (lane < 24) {   // 96 dw = 24 v4
            __builtin_amdgcn_global_load_lds((glb_u32_t*)(gt + lane * 4),
                                             (lds_u32_t*)(&st[wid][b][lane * 4]), 16, 0, 0);
        }
    };

    auto COMPUTE = [&](int b) {
        const float* row = &sp[wid][b][c * PS];
        const float* t   = &st[wid][b][c * 6];

        // 20 interleaved logits: class = g + 4*j
        float x[20];
        #pragma unroll
        for (int j = 0; j < 20; ++j) x[j] = row[5 + g + 4 * j];

        float m01 = fmaxf(x[0], x[1]),  m23 = fmaxf(x[2], x[3]);
        float m45 = fmaxf(x[4], x[5]),  m67 = fmaxf(x[6], x[7]);
        float m89 = fmaxf(x[8], x[9]),  mab = fmaxf(x[10], x[11]);
        float mcd = fmaxf(x[12], x[13]), mef = fmaxf(x[14], x[15]);
        float mgh = fmaxf(x[16], x[17]), mij = fmaxf(x[18], x[19]);
        float ma = fmaxf(fmaxf(m01, m23), fmaxf(m45, m67));
        float mb = fmaxf(fmaxf(m89, mab), fmaxf(mcd, mef));
        float m  = fmaxf(fmaxf(ma, mb), fmaxf(mgh, mij));
        m = fmaxf(m, __shfl_xor(m, 1));
        m = fmaxf(m, __shfl_xor(m, 2));

        int lbl = (int)t[5];

        float seA = 0.f, seB = 0.f, sel = 0.f;
        #pragma unroll
        for (int j = 0; j < 20; j += 2) {
            seA += __expf(x[j]     - m);
            seB += __expf(x[j + 1] - m);
            if (g + 4 * j     == lbl) sel = x[j];
        }
        #pragma unroll
        for (int j = 1; j < 20; j += 2)
            if (g + 4 * j == lbl) sel = x[j];
        float se = seA + seB;
        se  += __shfl_xor(se, 1);
        se  += __shfl_xor(se, 2);
        sel += __shfl_xor(sel, 1);
        sel += __shfl_xor(sel, 2);

        if (g == 0) {
            float t0 = t[0], t1 = t[1], t2 = t[2], t3 = t[3], t4 = t[4];
            float p0 = row[0], p1 = row[1], p2 = row[2], p3 = row[3], p4 = row[4];

            bool obj   = (t0 == 1.0f);
            bool noobj = (t0 == 0.0f);

            float bce = fmaxf(p0, 0.0f) - p0 * t0 + log1pf(__expf(-fabsf(p0)));

            float b1x1 = p0 - p2 * 0.5f, b1y1 = p1 - p3 * 0.5f;
            float b1x2 = p0 + p2 * 0.5f, b1y2 = p1 + p3 * 0.5f;
            float b2x1 = t1 - t3 * 0.5f, b2y1 = t2 - t4 * 0.5f;
            float b2x2 = t1 + t3 * 0.5f, b2y2 = t2 + t4 * 0.5f;
            float xi1 = fmaxf(b1x1, b2x1), yi1 = fmaxf(b1y1, b2y1);
            float xi2 = fminf(b1x2, b2x2), yi2 = fminf(b1y2, b2y2);
            float inter = fmaxf(xi2 - xi1, 0.0f) * fmaxf(yi2 - yi1, 0.0f);
            float a1 = fabsf((b1x2 - b1x1) * (b1y2 - b1y1));
            float a2 = fabsf((b2x2 - b2x1) * (b2y2 - b2y1));
            float iou = inter / (a1 + a2 - inter + 1e-6f);

            float pobj = 1.0f / (1.0f + __expf(-p0));
            float dob  = pobj - iou * t0;

            float d1 = 1.0f / (1.0f + __expf(-p1)) - t1;
            float d2 = 1.0f / (1.0f + __expf(-p2)) - t2;
            float d3 = 1.0f / (1.0f + __expf(-p3)) - t3;
            float d4 = 1.0f / (1.0f + __expf(-p4)) - t4;
            float boxse = d1*d1 + d2*d2 + d3*d3 + d4*d4;

            float nll = __logf(se) - (sel - m);

            if (noobj) { s0 += bce; s1 += 1.0f; }
            if (obj)   { s2 += dob * dob; s3 += 1.0f; s4 += boxse; s5 += nll; }
        }
    };

    // ---- per-wave pipeline: depth 3 ring, 2 chunks prefetched ahead ----
    STAGE(0, gw);
    if (n > 1) STAGE(1, gw + NWAVES);

    for (int i = 0; i < n; ++i) {
        if (i + 2 < n) STAGE((i + 2) % 3, gw + (size_t)(i + 2) * NWAVES);

        int infl = n - 1 - i;            // chunks outstanding beyond i
        if (infl > 2) infl = 2;
        if (infl == 2)      asm volatile("s_waitcnt vmcnt(14)" ::: "memory");
        else if (infl == 1) asm volatile("s_waitcnt vmcnt(7)"  ::: "memory");
        else                asm volatile("s_waitcnt vmcnt(0)"  ::: "memory");
        __builtin_amdgcn_sched_barrier(0);

        COMPUTE(i % 3);
    }

    // ---- wave reduction: data lives only on lanes ≡ 0 (mod 4) ----
    #pragma unroll
    for (int off = 4; off <= 32; off <<= 1) {
        s0 += __shfl_down(s0, off);
        s1 += __shfl_down(s1, off);
        s2 += __shfl_down(s2, off);
        s3 += __shfl_down(s3, off);
        s4 += __shfl_down(s4, off);
        s5 += __shfl_down(s5, off);
    }

    __syncthreads();
    if (lane == 0) {
        red[wid][0] = s0; red[wid][1] = s1; red[wid][2] = s2;
        red[wid][3] = s3; red[wid][4] = s4; red[wid][5] = s5;
    }
    __syncthreads();
    if (tid == 0) {
        float a0=0.f,a1=0.f,a2=0.f,a3=0.f,a4=0.f,a5=0.f;
        #pragma unroll
        for (int w = 0; w < 4; ++w) {
            a0 += red[w][0]; a1 += red[w][1]; a2 += red[w][2];
            a3 += red[w][3]; a4 += red[w][4]; a5 += red[w][5];
        }
        float4* slot = (float4*)(part + (size_t)blockIdx.x * 8);
        slot[0] = make_float4(a0, a1, a2, a3);
        slot[1] = make_float4(a4, a5, 0.0f, 0.0f);
    }

    __threadfence();
    cg::this_grid().sync();

    // ---- block 0: final reduce over GRID slots + loss computation ----
    if (blockIdx.x == 0) {
        float a0=0.f,a1=0.f,a2=0.f,a3=0.f,a4=0.f,a5=0.f;
        for (int i = tid; i < GRID; i += TPB) {
            const float4* slot = (const float4*)(part + (size_t)i * 8);
            float4 v0 = slot[0];
            float4 v1 = slot[1];
            a0 += v0.x; a1 += v0.y; a2 += v0.z;
            a3 += v0.w; a4 += v1.x; a5 += v1.y;
        }
        #pragma unroll
        for (int off = 32; off > 0; off >>= 1) {
            a0 += __shfl_down(a0, off);
            a1 += __shfl_down(a1, off);
            a2 += __shfl_down(a2, off);
            a3 += __shfl_down(a3, off);
            a4 += __shfl_down(a4, off);
            a5 += __shfl_down(a5, off);
        }
        __syncthreads();   // red[] reuse
        if (lane == 0) {
            red[wid][0] = a0; red[wid][1] = a1; red[wid][2] = a2;
            red[wid][3] = a3; red[wid][4] = a4; red[wid][5] = a5;
        }
        __syncthreads();
        if (tid == 0) {
            float b0=0.f,b1=0.f,b2=0.f,b3=0.f,b4=0.f,b5=0.f;
            #pragma unroll
            for (int w = 0; w < 4; ++w) {
                b0 += red[w][0]; b1 += red[w][1]; b2 += red[w][2];
                b3 += red[w][3]; b4 += red[w][4]; b5 += red[w][5];
            }
            float n_noobj = b1;
            float n_obj   = b3;
            // return order: (5*box, 1*object, 0.5*noobj, 1*class)
            out[0] = 5.0f * b4 / fmaxf(n_obj * 4.0f, 1.0f);
            out[1] = 1.0f * b2 / fmaxf(n_obj, 1.0f);
            out[2] = 0.5f * b0 / fmaxf(n_noobj, 1.0f);
            out[3] = 1.0f * b5 / fmaxf(n_obj, 1.0f);
        }
    }
}

extern "C" void kernel_launch(void* const* d_in, const int* in_sizes, int n_in,
                              void* d_out, int out_size, void* d_ws, size_t ws_size,
                              hipStream_t stream)
{
    const float* pred = (const float*)d_in[0];
    const float* tgt  = (const float*)d_in[1];
    float* out  = (float*)d_out;
    float* part = (float*)d_ws;   // needs GRID*8*4 = 16,384 B

    void* args[] = { (void*)&pred, (void*)&tgt, (void*)&part, (void*)&out };
    hipLaunchCooperativeKernel((void*)yolo_fused, dim3(GRID), dim3(TPB),
                               args, 0, stream);
}

// Round 9
// 24.318 us; speedup vs baseline: 5.5614x; 5.5614x over previous
//
#include <hip/hip_runtime.h>
#include <math.h>
#include <stdint.h>

// Problem constants (from reference): B=32, A=3, S=52, C=80
constexpr int NCELL = 32 * 3 * 52 * 52;   // 259584 = 256 * 1014
constexpr int PS = 85;                    // prediction channels (5 + C)
constexpr int TPB = 256;
constexpr int NBLK = NCELL / TPB;         // 1014

// d_ws: per-block partials, 8 floats (32 B) per block; NBLK slots.
// [b*8 + 0..5] = {bce_noobj, n_noobj, obj_term, n_obj, box_se, nll}

__global__ __launch_bounds__(TPB) void yolo_main(const float* __restrict__ pred,
                                                 const float* __restrict__ tgt,
                                                 float* __restrict__ part)
{
    const int tid  = threadIdx.x;
    const int wid  = tid >> 6;
    const int lane = tid & 63;
    const int cell = blockIdx.x * TPB + tid;            // one cell per thread

    // ---- load p0..p4 via two ALIGNED float4s covering dwords [85c&~3, +8) ----
    // 85c mod 4 == c mod 4, and the window always contains 85c..85c+4.
    const int pbase = cell * PS;                        // dword index of row
    const float4* pa = (const float4*)pred;
    const int pi = pbase >> 2;
    float4 A = pa[pi];
    float4 Bv = pa[pi + 1];
    const int o = cell & 3;
    float p0 = o==0 ? A.x  : o==1 ? A.y  : o==2 ? A.z  : A.w;
    float p1 = o==0 ? A.y  : o==1 ? A.z  : o==2 ? A.w  : Bv.x;
    float p2 = o==0 ? A.z  : o==1 ? A.w  : o==2 ? Bv.x : Bv.y;
    float p3 = o==0 ? A.w  : o==1 ? Bv.x : o==2 ? Bv.y : Bv.z;
    float p4 = o==0 ? Bv.x : o==1 ? Bv.y : o==2 ? Bv.z : Bv.w;

    // ---- load t0..t5 via two ALIGNED float4s covering dwords [6c&~3, +8) ----
    // 6c mod 4 = 2*(c&1) in {0,2}.
    const int tbase = cell * 6;
    const float4* pt = (const float4*)tgt;
    const int ti = tbase >> 2;
    float4 TA = pt[ti];
    float4 TB = pt[ti + 1];
    const bool oh = (cell & 1);
    float t0 = oh ? TA.z : TA.x;
    float t1 = oh ? TA.w : TA.y;
    float t2 = oh ? TB.x : TA.z;
    float t3 = oh ? TB.y : TA.w;
    float t4 = oh ? TB.z : TB.x;
    float t5 = oh ? TB.w : TB.y;

    const bool obj   = (t0 == 1.0f);
    const bool noobj = (t0 == 0.0f);

    float s0=0.f, s1=0.f, s2=0.f, s3=0.f, s4=0.f, s5=0.f;

    // ---- cheap per-cell terms ----
    {
        // BCE-with-logits on objectness (noobj contribution)
        float bce = fmaxf(p0, 0.0f) - p0 * t0 + log1pf(__expf(-fabsf(p0)));

        // midpoint IoU: b1 = pred[0:4], b2 = target[1:5]
        float b1x1 = p0 - p2 * 0.5f, b1y1 = p1 - p3 * 0.5f;
        float b1x2 = p0 + p2 * 0.5f, b1y2 = p1 + p3 * 0.5f;
        float b2x1 = t1 - t3 * 0.5f, b2y1 = t2 - t4 * 0.5f;
        float b2x2 = t1 + t3 * 0.5f, b2y2 = t2 + t4 * 0.5f;
        float xi1 = fmaxf(b1x1, b2x1), yi1 = fmaxf(b1y1, b2y1);
        float xi2 = fminf(b1x2, b2x2), yi2 = fminf(b1y2, b2y2);
        float inter = fmaxf(xi2 - xi1, 0.0f) * fmaxf(yi2 - yi1, 0.0f);
        float a1 = fabsf((b1x2 - b1x1) * (b1y2 - b1y1));
        float a2 = fabsf((b2x2 - b2x1) * (b2y2 - b2y1));
        float iou = inter / (a1 + a2 - inter + 1e-6f);

        float pobj = 1.0f / (1.0f + __expf(-p0));
        float dob  = pobj - iou * t0;

        float d1 = 1.0f / (1.0f + __expf(-p1)) - t1;
        float d2 = 1.0f / (1.0f + __expf(-p2)) - t2;
        float d3 = 1.0f / (1.0f + __expf(-p3)) - t3;
        float d4 = 1.0f / (1.0f + __expf(-p4)) - t4;
        float boxse = d1*d1 + d2*d2 + d3*d3 + d4*d4;

        if (noobj) { s0 = bce; s1 = 1.0f; }
        if (obj)   { s2 = dob * dob; s4 = boxse; }
    }

    // ---- wave-cooperative softmax for obj cells only (~5%) ----
    unsigned long long mask = __ballot(obj);
    if (lane == 0) s3 = (float)__popcll(mask);          // n_obj for this wave

    const int waveCell0 = blockIdx.x * TPB + wid * 64;
    while (mask) {
        int L = __builtin_ctzll(mask);                  // wave-uniform owner lane
        mask &= mask - 1;

        const float* row = pred + (size_t)(waveCell0 + L) * PS;
        // 80 logits: lanes 0..63 read class=lane, lanes 0..15 also class=64+lane
        float v0 = row[5 + lane];
        float v1 = (lane < 16) ? row[69 + lane] : -INFINITY;

        // wave max
        float m = fmaxf(v0, v1);
        #pragma unroll
        for (int off = 1; off < 64; off <<= 1)
            m = fmaxf(m, __shfl_xor(m, off));

        // wave sum of exp
        float e = __expf(v0 - m) + ((lane < 16) ? __expf(v1 - m) : 0.0f);
        #pragma unroll
        for (int off = 1; off < 64; off <<= 1)
            e += __shfl_xor(e, off);

        // label logit
        int lbl = (int)__shfl(t5, L);
        float sel = (lbl < 64) ? __shfl(v0, lbl) : __shfl(v1, lbl - 64);

        if (lane == 0) s5 += __logf(e) - (sel - m);
    }

    // ---- wave butterfly reduction of the 6 partials ----
    #pragma unroll
    for (int off = 1; off < 64; off <<= 1) {
        s0 += __shfl_xor(s0, off);
        s1 += __shfl_xor(s1, off);
        s2 += __shfl_xor(s2, off);
        s3 += __shfl_xor(s3, off);
        s4 += __shfl_xor(s4, off);
        s5 += __shfl_xor(s5, off);
    }

    // ---- cross-wave reduction (4 waves), one float4-pair store per block ----
    __shared__ float red[4][6];
    if (lane == 0) {
        red[wid][0] = s0; red[wid][1] = s1; red[wid][2] = s2;
        red[wid][3] = s3; red[wid][4] = s4; red[wid][5] = s5;
    }
    __syncthreads();
    if (tid == 0) {
        float a0=0.f,a1=0.f,a2=0.f,a3=0.f,a4=0.f,a5=0.f;
        #pragma unroll
        for (int w = 0; w < 4; ++w) {
            a0 += red[w][0]; a1 += red[w][1]; a2 += red[w][2];
            a3 += red[w][3]; a4 += red[w][4]; a5 += red[w][5];
        }
        float4* slot = (float4*)(part + (size_t)blockIdx.x * 8);
        slot[0] = make_float4(a0, a1, a2, a3);
        slot[1] = make_float4(a4, a5, 0.0f, 0.0f);
    }
}

// Reduction over NBLK partial sets + final loss computation.
__global__ __launch_bounds__(1024) void yolo_reduce(const float* __restrict__ part,
                                                    float* __restrict__ out)
{
    float a0=0.f,a1=0.f,a2=0.f,a3=0.f,a4=0.f,a5=0.f;
    int i = threadIdx.x;
    if (i < NBLK) {
        const float4* slot = (const float4*)(part + (size_t)i * 8);
        float4 v0 = slot[0];
        float4 v1 = slot[1];
        a0 = v0.x; a1 = v0.y; a2 = v0.z; a3 = v0.w; a4 = v1.x; a5 = v1.y;
    }

    #pragma unroll
    for (int off = 32; off > 0; off >>= 1) {
        a0 += __shfl_down(a0, off);
        a1 += __shfl_down(a1, off);
        a2 += __shfl_down(a2, off);
        a3 += __shfl_down(a3, off);
        a4 += __shfl_down(a4, off);
        a5 += __shfl_down(a5, off);
    }

    __shared__ float red[16][6];
    int lane = threadIdx.x & 63;
    int wid  = threadIdx.x >> 6;
    if (lane == 0) {
        red[wid][0] = a0; red[wid][1] = a1; red[wid][2] = a2;
        red[wid][3] = a3; red[wid][4] = a4; red[wid][5] = a5;
    }
    __syncthreads();
    if (threadIdx.x == 0) {
        float b0=0.f,b1=0.f,b2=0.f,b3=0.f,b4=0.f,b5=0.f;
        #pragma unroll
        for (int w = 0; w < 16; ++w) {
            b0 += red[w][0]; b1 += red[w][1]; b2 += red[w][2];
            b3 += red[w][3]; b4 += red[w][4]; b5 += red[w][5];
        }
        float n_noobj = b1;
        float n_obj   = b3;
        // return order: (5*box, 1*object, 0.5*noobj, 1*class)
        out[0] = 5.0f * b4 / fmaxf(n_obj * 4.0f, 1.0f);
        out[1] = 1.0f * b2 / fmaxf(n_obj, 1.0f);
        out[2] = 0.5f * b0 / fmaxf(n_noobj, 1.0f);
        out[3] = 1.0f * b5 / fmaxf(n_obj, 1.0f);
    }
}

extern "C" void kernel_launch(void* const* d_in, const int* in_sizes, int n_in,
                              void* d_out, int out_size, void* d_ws, size_t ws_size,
                              hipStream_t stream)
{
    const float* pred = (const float*)d_in[0];
    const float* tgt  = (const float*)d_in[1];
    float* out  = (float*)d_out;
    float* part = (float*)d_ws;   // needs NBLK*8*4 = 32,448 B

    yolo_main<<<NBLK, TPB, 0, stream>>>(pred, tgt, part);
    yolo_reduce<<<1, 1024, 0, stream>>>(part, out);
}